// Round 6
// baseline (462.598 us; speedup 1.0000x reference)
//
#include <hip/hip_runtime.h>

typedef __bf16 bf16x8 __attribute__((ext_vector_type(8)));
typedef float floatx4 __attribute__((ext_vector_type(4)));
typedef float floatx16 __attribute__((ext_vector_type(16)));

__device__ __forceinline__ unsigned short f2bf(float x) {
  union { float f; unsigned u; } v; v.f = x;
  unsigned u = v.u;
  unsigned r = (u + 0x7FFFu + ((u >> 16) & 1u)) >> 16;
  return (unsigned short)r;
}
__device__ __forceinline__ float bf2f(unsigned short x) {
  union { unsigned u; float f; } v; v.u = ((unsigned)x) << 16;
  return v.f;
}
__device__ __forceinline__ float fast_rcp(float x) {
#if defined(__has_builtin) && __has_builtin(__builtin_amdgcn_rcpf)
  return __builtin_amdgcn_rcpf(x);
#else
  return 1.0f / x;
#endif
}
__device__ __forceinline__ float fast_rsq(float x) {
#if defined(__has_builtin) && __has_builtin(__builtin_amdgcn_rsqf)
  return __builtin_amdgcn_rsqf(x);
#else
  return 1.0f / sqrtf(x);
#endif
}

// ---- async global->LDS staging (16B/lane, wave-uniform LDS base) ----
__device__ __forceinline__ void stage16(const unsigned short* __restrict__ g,
                                        unsigned short* s, int lane) {
#if defined(__has_builtin) && __has_builtin(__builtin_amdgcn_global_load_lds)
  __builtin_amdgcn_global_load_lds((const __attribute__((address_space(1))) void*)g,
                                   (__attribute__((address_space(3))) void*)s,
                                   16, 0, 0);
#else
  *(uint4*)(s + (size_t)lane * 8) = *(const uint4*)g;
#endif
}

// ---- fp32 -> bf16 elementwise convert (float4 loads) ----
__global__ void cvt_bf16(const float* __restrict__ in, unsigned short* __restrict__ out, int n4) {
  int i = blockIdx.x * 256 + threadIdx.x;
  if (i >= n4) return;
  const float4 v = ((const float4*)in)[i];
  ushort4 o;
  o.x = f2bf(v.x); o.y = f2bf(v.y); o.z = f2bf(v.z); o.w = f2bf(v.w);
  ((ushort4*)out)[i] = o;
}

// ---- fp32 W[n][k] (1024x1024) -> bf16 MFMA-B-fragment pack ----
// frag (cb=n>>5, kb=k>>4): lane = ((k>>3)&1)*32 + (n&31), j = k&7.
// elem addr = ((cb*64 + kb)*64 + lane)*8 + j   (KB = 1024/16 = 64)
__global__ void cvt_pack_w(const float* __restrict__ W, unsigned short* __restrict__ Bp) {
  int i = blockIdx.x * 256 + threadIdx.x;  // 4-elem groups, 262144 total
  int n = i >> 8;
  int k4 = (i & 255) * 4;
  const float4 v = *(const float4*)(W + (size_t)n * 1024 + k4);
  const int base = (((n >> 5) * 64 + (k4 >> 4)) * 64 + ((k4 >> 3) & 1) * 32 + (n & 31)) * 8 + (k4 & 7);
  ushort4 o; o.x = f2bf(v.x); o.y = f2bf(v.y); o.z = f2bf(v.z); o.w = f2bf(v.w);
  *(ushort4*)(Bp + base) = o;
}

// ============================================================================
// v6: 256x256 bf16 GEMM, MFMA 32x32x16, A via LDS, B DIRECT FROM L2.
//
// R2-R5 evidence: schedule-invariant 34-36% MfmaUtil => LDS-read-throughput
// bound (192 b128/K-tile/CU ~ 2300cy floor vs 620cy MFMA floor). Fix: remove
// B from LDS entirely. B is L2-resident (Wq/Wk 2MB, Gt 4MB) and PRE-PACKED in
// fragment order, so a wave's B-frag load = 1 coalesced dwordx4/lane from L2.
// LDS now stages only A (64KB dbuf). LDS floor ~1800cy, MFMA floor ~516cy.
//
// Geometry: BM=BN=256, BK=64, 8 waves (2M x 4N), wave tile 128x64 = 2mh x
// 2rb x 2nb blocks of 32x32. acc = 8 x floatx16.
// A-frag (32x32x16): row = base + (lane&31), k = ks*16 + (lane>>5)*8 + j;
// LDS slot = (2ks | lane>>5) ^ (row&7) (row-XOR swizzle; uniform 8 lanes/slot
// => conflict-free). C/D: col = lane&31, row = (reg&3)+8*(reg>>2)+4*(lane>>5).
//
// Per tile t: { load B(t) regs (8 dwordx4); stage A(t+1) (4 gload_lds);
// 4 x [4 ds_read_b128 + 8 MFMA]; vmcnt(0); barrier }. Stages have a full
// tile (~2000cy) in flight; vmcnt(0) retires own-wave ops only. NO spills.
// ============================================================================
#define LDSE2 (256 * 64)
#define BAR() __builtin_amdgcn_s_barrier()

#define STAGE_A(b, mh, t) {                                                    \
  stage16(gA + (size_t)((mh) * 128) * K + (size_t)(t) * 64,                    \
          sAw + (b) * LDSE2 + ((mh) * 128) * 64, lane);                        \
  stage16(gA + (size_t)((mh) * 128 + 8) * K + (size_t)(t) * 64,                \
          sAw + (b) * LDSE2 + ((mh) * 128 + 8) * 64, lane); }

#define LOAD_B(t) {                                                            \
  _Pragma("unroll") for (int nb = 0; nb < 2; ++nb) {                           \
    _Pragma("unroll") for (int ks = 0; ks < 4; ++ks) {                         \
      bq[nb][ks] = *(const bf16x8*)(gBl +                                      \
          ((size_t)(cb0 + nb) * KB + ((t) * 4 + ks)) * 512);                   \
    } } }

#define KSTEP(b, ks) {                                                         \
  _Pragma("unroll") for (int mh = 0; mh < 2; ++mh) {                           \
    _Pragma("unroll") for (int rb = 0; rb < 2; ++rb) {                         \
      af[mh * 2 + rb] = *(const bf16x8*)(rA + (b) * LDSE2 +                    \
          (mh * 128 + rb * 32) * 64 + ((((ks) * 2) | hi) ^ key) * 8);          \
    } }                                                                        \
  __builtin_amdgcn_s_setprio(1);                                               \
  _Pragma("unroll") for (int mh = 0; mh < 2; ++mh) {                           \
    _Pragma("unroll") for (int rb = 0; rb < 2; ++rb) {                         \
      _Pragma("unroll") for (int nb = 0; nb < 2; ++nb) {                       \
        acc[mh][rb][nb] = __builtin_amdgcn_mfma_f32_32x32x16_bf16(             \
            af[mh * 2 + rb], bq[nb][ks], acc[mh][rb][nb], 0, 0, 0);            \
      } } }                                                                    \
  __builtin_amdgcn_s_setprio(0); }

#define TILE6(b, t, S, Y) {                                                    \
  LOAD_B(t);                                                                   \
  if (S) { STAGE_A((b) ^ 1, 0, (t) + 1); STAGE_A((b) ^ 1, 1, (t) + 1); }       \
  KSTEP(b, 0); KSTEP(b, 1); KSTEP(b, 2); KSTEP(b, 3);                          \
  if (Y) { asm volatile("s_waitcnt vmcnt(0)" ::: "memory"); BAR(); } }

template <int OUT_BF16>
__global__ __launch_bounds__(512, 2) void gemm32(const unsigned short* __restrict__ A,
                                                 const unsigned short* __restrict__ Bp,
                                                 const unsigned short* __restrict__ Bp2,
                                                 const float* __restrict__ bias,
                                                 const float* __restrict__ bias2,
                                                 void* __restrict__ Cv,
                                                 int M, int N, int K, int halfM) {
  __shared__ __align__(16) unsigned short As[2 * 256 * 64];  // 64 KB
  const int tid = threadIdx.x;
  const int w = tid >> 6;
  const int lane = tid & 63;

  const int NT = N >> 8;
  const int id = blockIdx.x;
  const int x = id & 7;
  const int g = id >> 3;
  const int nt_ = g % NT;
  const int mt = x + 8 * (g / NT);
  const int bm = mt * 256, bn = nt_ * 256;

  const unsigned short* Bf = (bm >= halfM) ? Bp2 : Bp;
  const float* biasp = (bm >= halfM) ? bias2 : bias;

  const int key = lane & 7, hi = lane >> 5;
  const int l8 = lane >> 3;
  const int swz = ((lane & 7) ^ l8) * 8;  // pre-swizzled global k-offset

  const unsigned short* gA = A + (size_t)(bm + 16 * w + l8) * K + swz;
  unsigned short* sAw = As + (16 * w) * 64;
  const unsigned short* rA = As + ((w >> 2) * 64 + (lane & 31)) * 64;

  const int KB = K >> 4;
  const int cb0 = (bn >> 5) + (w & 3) * 2;
  const unsigned short* gBl = Bf + (size_t)lane * 8;

  floatx16 acc[2][2][2] = {};   // [mh][rb][nb]
  bf16x8 af[4], bq[2][4];

  // prologue: stage A tile 0, publish
  STAGE_A(0, 0, 0); STAGE_A(0, 1, 0);
  asm volatile("s_waitcnt vmcnt(0)" ::: "memory");
  BAR();

  const int ntl = K >> 6;  // 16 (proj) or 32 (final), always even
  for (int it = 0; it < (ntl >> 1) - 1; ++it) {
    TILE6(0, 2 * it, true, true);
    TILE6(1, 2 * it + 1, true, true);
  }
  TILE6(0, ntl - 2, true, true);
  TILE6(1, ntl - 1, false, false);

  // epilogue: C/D col=lane&31, row=(reg&3)+8*(reg>>2)+4*(lane>>5)
#pragma unroll
  for (int nb = 0; nb < 2; ++nb) {
    const int gcol = bn + (w & 3) * 64 + nb * 32 + (lane & 31);
    const float bb = biasp ? biasp[gcol] : 0.0f;
#pragma unroll
    for (int mh = 0; mh < 2; ++mh) {
#pragma unroll
      for (int rb = 0; rb < 2; ++rb) {
        const int rbase = bm + mh * 128 + (w >> 2) * 64 + rb * 32 + 4 * hi;
#pragma unroll
        for (int r = 0; r < 16; ++r) {
          const int grow = rbase + (r & 3) + 8 * (r >> 2);
          float v = acc[mh][rb][nb][r] + bb;
          if (OUT_BF16)
            ((unsigned short*)Cv)[(size_t)grow * N + gcol] = f2bf(v);
          else
            ((float*)Cv)[(size_t)grow * N + gcol] = v;
        }
      }
    }
  }
}

// ---- scan pass 1: per-chunk partial sums (64 chunks x 64 rows) ----
__global__ void scan_partial(const unsigned short* __restrict__ proj, float* __restrict__ partial) {
  const int t = blockIdx.x, chunk = blockIdx.y, b = blockIdx.z;
  const int c4 = threadIdx.x * 4;
  const unsigned short* p =
      proj + ((size_t)t * 4 + b) * 4096 * 1024 + (size_t)chunk * 64 * 1024 + c4;
  float4 s = {0.f, 0.f, 0.f, 0.f};
  for (int i = 0; i < 64; i++) {
    const ushort4 v = *(const ushort4*)(p + (size_t)i * 1024);
    s.x += bf2f(v.x); s.y += bf2f(v.y); s.z += bf2f(v.z); s.w += bf2f(v.w);
  }
  *(float4*)(partial + ((size_t)(t * 4 + b) * 64 + chunk) * 1024 + c4) = s;
}

// ---- scan pass 2: prefix + running mean + head L2-norm + pack ----
__global__ void scan_apply(const unsigned short* __restrict__ proj,
                           const float* __restrict__ partial,
                           unsigned short* __restrict__ qkn) {
  const int t = blockIdx.x, chunk = blockIdx.y, b = blockIdx.z;
  const int c4 = threadIdx.x * 4;
  const float* pp = partial + (size_t)(t * 4 + b) * 64 * 1024 + c4;
  float4 run = {0.f, 0.f, 0.f, 0.f};
  for (int j = 0; j < chunk; j++) {
    const float4 v = *(const float4*)(pp + (size_t)j * 1024);
    run.x += v.x; run.y += v.y; run.z += v.z; run.w += v.w;
  }
  const unsigned short* p =
      proj + ((size_t)t * 4 + b) * 4096 * 1024 + (size_t)chunk * 64 * 1024 + c4;
  unsigned short* o = qkn + (size_t)b * 4096 * 2048 + (size_t)chunk * 64 * 2048 + t * 1024 + c4;
  for (int i = 0; i < 64; i++) {
    const ushort4 v = *(const ushort4*)(p + (size_t)i * 1024);
    run.x += bf2f(v.x); run.y += bf2f(v.y); run.z += bf2f(v.z); run.w += bf2f(v.w);
    const int s = chunk * 64 + i;
    const float inv = fast_rcp((float)(s + 1));
    const float a0 = run.x * inv, a1 = run.y * inv, a2 = run.z * inv, a3 = run.w * inv;
    float sq = a0 * a0 + a1 * a1 + a2 * a2 + a3 * a3;
    sq += __shfl_xor(sq, 8);
    sq += __shfl_xor(sq, 4);
    sq += __shfl_xor(sq, 2);
    sq += __shfl_xor(sq, 1);
    const float sc = fast_rsq(fmaxf(sq, 1e-24f));
    ushort4 ov;
    ov.x = f2bf(a0 * sc); ov.y = f2bf(a1 * sc); ov.z = f2bf(a2 * sc); ov.w = f2bf(a3 * sc);
    *(ushort4*)(o + (size_t)i * 2048) = ov;
  }
}

// ---- tiny precomputes: A[t][h] = W(e/r)[h] @ Wc[:, t*32:+32]^T  (64x64 each) ----
__global__ void make_A(const float* __restrict__ We, const float* __restrict__ Wr,
                       const float* __restrict__ Wc, float* __restrict__ Asm) {
  const int t = blockIdx.x >> 4, h = blockIdx.x & 15;
  const float* W = (t ? Wr : We) + (size_t)h * 64 * 32;
  for (int e = threadIdx.x; e < 4096; e += 256) {
    const int d = e >> 6, dk = e & 63;
    float s = 0.f;
    for (int r = 0; r < 32; r++) s += W[d * 32 + r] * Wc[dk * 64 + t * 32 + r];
    Asm[(size_t)blockIdx.x * 4096 + e] = s;
  }
}

// ---- Gt[f][k] = sum_dk A[t][h][d][dk] * Wo[f][h*64+dk], k = t*1024+h*64+d ----
// Output written in MFMA-B-fragment pack (KB = 2048/16 = 128).
__global__ __launch_bounds__(256) void make_G(const float* __restrict__ Asm,
                                              const float* __restrict__ Wo,
                                              unsigned short* __restrict__ Gp) {
  __shared__ float At[64 * 65];    // At[dk][d], padded
  __shared__ float WoSh[64 * 64];  // WoSh[fl][dk]
  const int th = blockIdx.x, t = th >> 4, h = th & 15;
  const int f0 = blockIdx.y * 64;
  const int tid = threadIdx.x;
  for (int e = tid; e < 4096; e += 256) {
    const int d = e >> 6, dk = e & 63;
    At[dk * 65 + d] = Asm[(size_t)th * 4096 + e];
  }
  for (int e = tid; e < 4096; e += 256) {
    const int fl = e >> 6, dk = e & 63;
    WoSh[e] = Wo[(size_t)(f0 + fl) * 1024 + h * 64 + dk];
  }
  __syncthreads();
  const int d = tid & 63;
  const int fsub = tid >> 6;  // 0..3
#pragma unroll 4
  for (int it = 0; it < 16; ++it) {
    const int fl = it * 4 + fsub;
    float s = 0.f;
#pragma unroll
    for (int dk4 = 0; dk4 < 16; ++dk4) {
      const float4 wv = *(const float4*)&WoSh[fl * 64 + dk4 * 4];
      s += At[(dk4 * 4 + 0) * 65 + d] * wv.x + At[(dk4 * 4 + 1) * 65 + d] * wv.y +
           At[(dk4 * 4 + 2) * 65 + d] * wv.z + At[(dk4 * 4 + 3) * 65 + d] * wv.w;
    }
    const int f = f0 + fl;
    const int k = t * 1024 + h * 64 + d;
    Gp[(((f >> 5) * 128 + (k >> 4)) * 64 + ((k >> 3) & 1) * 32 + (f & 31)) * 8 + (k & 7)] = f2bf(s);
  }
}

// ---- c0[f] = bo[f] + sum_j bc[j&63]*Wo[f][j]; one wave per f ----
__global__ void make_c0(const float* __restrict__ bc, const float* __restrict__ bo,
                        const float* __restrict__ Wo, float* __restrict__ c0) {
  const int f = blockIdx.x * 4 + (threadIdx.x >> 6);
  const int lane = threadIdx.x & 63;
  const float bcl = bc[lane];
  float s = 0.f;
  for (int j = lane; j < 1024; j += 64) s += bcl * Wo[(size_t)f * 1024 + j];
#pragma unroll
  for (int off = 32; off; off >>= 1) s += __shfl_xor(s, off);
  if (lane == 0) c0[f] = s + bo[f];
}

extern "C" void kernel_launch(void* const* d_in, const int* in_sizes, int n_in,
                              void* d_out, int out_size, void* d_ws, size_t ws_size,
                              hipStream_t stream) {
  const float* query = (const float*)d_in[0];
  const float* key_  = (const float*)d_in[1];
  const float* Wq = (const float*)d_in[4];
  const float* bq = (const float*)d_in[5];
  const float* Wk = (const float*)d_in[6];
  const float* bk = (const float*)d_in[7];
  const float* We = (const float*)d_in[10];
  const float* Wr = (const float*)d_in[11];
  const float* Wc = (const float*)d_in[13];
  const float* bc = (const float*)d_in[14];
  const float* Wo = (const float*)d_in[15];
  const float* bo = (const float*)d_in[16];

  // ws layout (max 76.1 MB)
  char* ws = (char*)d_ws;
  unsigned short* qkbf = (unsigned short*)ws;               // 67MB: q/k bf16, later QKn (16384x2048)
  unsigned short* Wbf  = (unsigned short*)(ws + 67108864);  // 4MB: Wq,Wk bf16 frag-packed
  unsigned short* Gp   = (unsigned short*)(ws + 71303168);  // 4MB: Gt frag-packed (1024x2048)
  float* partial       = (float*)(ws + 71303168);           // 2MB, OVERLAYS Gp (dead before make_G)
  float* Asm           = (float*)(ws + 75497472);           // 512KB
  float* c0            = (float*)(ws + 76021760);           // 4KB

  unsigned short* proj = (unsigned short*)d_out;  // d_out as scratch for bf16 projections

  // 1) fp32 -> bf16 (A-side linear; B-side fragment-packed)
  cvt_bf16<<<16384, 256, 0, stream>>>(query, qkbf, 4194304);
  cvt_bf16<<<16384, 256, 0, stream>>>(key_, qkbf + 16777216, 4194304);
  cvt_pack_w<<<1024, 256, 0, stream>>>(Wq, Wbf);
  cvt_pack_w<<<1024, 256, 0, stream>>>(Wk, Wbf + 1048576);

  // 2) q+k projections merged: M=32768 (rows <16384 use Wq/bq, rest Wk/bk)
  gemm32<1><<<512, 512, 0, stream>>>(qkbf, Wbf, Wbf + 1048576, bq, bk, proj,
                                     32768, 1024, 1024, 16384);

  // 3) causal running mean + l2norm + pack into QKn
  scan_partial<<<dim3(2, 64, 4), 256, 0, stream>>>(proj, partial);
  scan_apply<<<dim3(2, 64, 4), 256, 0, stream>>>(proj, partial, qkbf);

  // 4) fold We/Wr/Wc/Wo into G (after scan: partial dead, Gp region free)
  make_A<<<32, 256, 0, stream>>>(We, Wr, Wc, Asm);
  make_G<<<dim3(32, 16), 256, 0, stream>>>(Asm, Wo, Gp);
  make_c0<<<256, 256, 0, stream>>>(bc, bo, Wo, c0);

  // 5) out = QKn @ G^T + c0  (M=16384, N=1024, K=2048), fp32 out
  gemm32<0><<<256, 512, 0, stream>>>(qkbf, Gp, Gp, c0, c0, (float*)d_out,
                                     16384, 1024, 2048, 16384 * 2);
}